// Round 6
// baseline (4773.843 us; speedup 1.0000x reference)
//
#include <hip/hip_runtime.h>

// STATE=4096, CDIM=1024, fan_in=5121. RK4 x 4 steps = 16 aug evals = 64
// strictly-sequential matvecs. This round: ONE persistent kernel (512 blocks
// x 512 thr, 64KB LDS => exactly 2 blocks/CU, co-residency by construction)
// with a software global barrier; next phase's weights are DMA'd into LDS
// BEFORE the barrier (raw s_barrier avoids the compiler's vmcnt(0) drain) so
// the weight stream overlaps the barrier wait. Cross-block data (x vectors)
// moves via agent-scope atomics only (LLC-coherent, no fences needed).
#define N      4096
#define NC     1024
#define STEPS  4
#define NBLK   512
#define TPB    512
#define CPB    8      // columns per block (512*8 = 4096)

typedef unsigned short us8 __attribute__((ext_vector_type(8)));

__device__ __forceinline__ float bf2f(unsigned short u) {
  union { unsigned int i; float f; } v; v.i = ((unsigned int)u) << 16; return v.f;
}
__device__ __forceinline__ unsigned short f2bf(float f) {
  union { float f; unsigned int i; } v; v.f = f;
  const unsigned int u = v.i;
  return (unsigned short)((u + 0x7FFFu + ((u >> 16) & 1u)) >> 16);  // RNE
}
__device__ __forceinline__ float sigf(float x) { return 1.0f / (1.0f + __expf(-x)); }

__device__ __forceinline__ void load16(const unsigned short* g, unsigned short* l) {
  __builtin_amdgcn_global_load_lds(
      (__attribute__((address_space(1))) void*)(g),
      (__attribute__((address_space(3))) void*)(l),
      16, 0, 0);
}
__device__ __forceinline__ float aload(const float* p) {
  return __hip_atomic_load(p, __ATOMIC_RELAXED, __HIP_MEMORY_SCOPE_AGENT);
}
__device__ __forceinline__ void astore(float* p, float v) {
  __hip_atomic_store(p, v, __ATOMIC_RELAXED, __HIP_MEMORY_SCOPE_AGENT);
}

// ---------------------------------------------------------------------------
// init: ycur=h, cp=bias, xA=sig(h), T=t-row (fp32 exact), rk=0, barrier=0
// ---------------------------------------------------------------------------
__global__ __launch_bounds__(256) void k_init(const float* __restrict__ h,
                                              const float* __restrict__ W1,
                                              const float* __restrict__ W2,
                                              const float* __restrict__ b1,
                                              const float* __restrict__ b2,
                                              float* __restrict__ ycur,
                                              float* __restrict__ cp1,
                                              float* __restrict__ cp2,
                                              float* __restrict__ xA,
                                              float* __restrict__ T1,
                                              float* __restrict__ T2,
                                              float* __restrict__ rk,
                                              unsigned int* __restrict__ bar) {
  const int j = blockIdx.x * 256 + threadIdx.x;
  if (j < N) {
    ycur[j] = h[j];
    cp1[j] = b1[j];
    cp2[j] = b2[j];
    xA[j] = sigf(h[j]);
    T1[j] = W1[(size_t)(NC + N) * N + j];   // row 5120 (t-row)
    T2[j] = W2[(size_t)(NC + N) * N + j];
  }
  if (j < 16) rk[j] = 0.f;
  if (j < 2) bar[j] = 0u;
}

// ---------------------------------------------------------------------------
// Transpose+convert: W state rows [NC, NC+N) fp32 -> Wt[col][row] bf16.
// ---------------------------------------------------------------------------
__global__ __launch_bounds__(256) void k_conv(const float* __restrict__ W1,
                                              const float* __restrict__ W2,
                                              unsigned short* __restrict__ Wt1,
                                              unsigned short* __restrict__ Wt2) {
  __shared__ float tile[64][65];
  const float* __restrict__ W = blockIdx.z ? W2 : W1;
  unsigned short* __restrict__ Wt = blockIdx.z ? Wt2 : Wt1;
  const int i0 = blockIdx.x * 64;   // state-row offset
  const int j0 = blockIdx.y * 64;   // column offset
  const int c = threadIdx.x & 63, rq = threadIdx.x >> 6;
#pragma unroll
  for (int m = 0; m < 16; ++m) {
    const int ii = (m << 2) + rq;
    tile[ii][c] = W[(size_t)(NC + i0 + ii) * N + j0 + c];
  }
  __syncthreads();
#pragma unroll
  for (int it = 0; it < 2; ++it) {
    const int lin = it * 256 + threadIdx.x;
    const int jj = lin >> 3, g = lin & 7;
    us8 o;
#pragma unroll
    for (int e = 0; e < 8; ++e) o[e] = f2bf(tile[g * 8 + e][jj]);
    *reinterpret_cast<us8*>(&Wt[(size_t)(j0 + jj) * N + i0 + g * 8]) = o;
  }
}

// ---------------------------------------------------------------------------
// cp += c @ W[0:NC]  (fp32, once). grid (16, 8, 2), block 256.
// ---------------------------------------------------------------------------
__global__ __launch_bounds__(256) void k_cpart(const float* __restrict__ W1,
                                               const float* __restrict__ W2,
                                               const float* __restrict__ c,
                                               float* __restrict__ cp1,
                                               float* __restrict__ cp2) {
  const float* __restrict__ W = blockIdx.z ? W2 : W1;
  float* __restrict__ cp = blockIdx.z ? cp2 : cp1;
  __shared__ float xs[128];
  __shared__ float red[8][256];
  const int tid = threadIdx.x;
  const int cb = blockIdx.x, rc = blockIdx.y;
  const int r0 = rc * 128;
  if (tid < 128) xs[tid] = c[r0 + tid];
  __syncthreads();
  const int cg = tid & 31, rg = tid >> 5;
  const float* __restrict__ wbase = W + (size_t)r0 * N + cb * 256 + cg * 8;
  float a[8] = {0,0,0,0,0,0,0,0};
#pragma unroll
  for (int k = 0; k < 16; ++k) {
    const int r = rg + (k << 3);
    const float xv = xs[r];
    const float4 wa = *reinterpret_cast<const float4*>(wbase + (size_t)r * N);
    const float4 wb = *reinterpret_cast<const float4*>(wbase + (size_t)r * N + 4);
    a[0] = fmaf(wa.x, xv, a[0]); a[1] = fmaf(wa.y, xv, a[1]);
    a[2] = fmaf(wa.z, xv, a[2]); a[3] = fmaf(wa.w, xv, a[3]);
    a[4] = fmaf(wb.x, xv, a[4]); a[5] = fmaf(wb.y, xv, a[5]);
    a[6] = fmaf(wb.z, xv, a[6]); a[7] = fmaf(wb.w, xv, a[7]);
  }
#pragma unroll
  for (int e = 0; e < 8; ++e) red[rg][cg * 8 + e] = a[e];
  __syncthreads();
  float ssum = 0.f;
#pragma unroll
  for (int g = 0; g < 8; ++g) ssum += red[g][tid];
  atomicAdd(&cp[cb * 256 + tid], ssum);
}

// ---------------------------------------------------------------------------
// Persistent ODE kernel. 512 blocks x 512 thr, 64 KB LDS (2 blocks/CU exact).
// Wave w owns rows [w*512,(w+1)*512); lane l owns rows rbase..rbase+7.
// Phases ph=0..63: mode=ph&3 (P1..P4), eval=ph>>2, matrix alternates W1/W2.
// red[] scratch aliases wave-0's LDS slice; ordered by __syncthreads.
// ---------------------------------------------------------------------------
__global__ __launch_bounds__(TPB, 4) void k_ode(
    const unsigned short* __restrict__ Wt1,
    const unsigned short* __restrict__ Wt2,
    const float* __restrict__ T1v, const float* __restrict__ T2v,
    const float* __restrict__ cp1, const float* __restrict__ cp2,
    float* __restrict__ xA, float* __restrict__ xB,
    float* __restrict__ fbuf, float* __restrict__ ycur,
    float* __restrict__ ksum, float* __restrict__ rk,
    const float* __restrict__ tptr,
    unsigned int* __restrict__ bar,
    float* __restrict__ out) {
  __shared__ unsigned short wlds[CPB][N];   // 65536 B exactly
  float* red = (float*)&wlds[0][0];         // 72 floats, aliased (see syncs)

  const int tid = threadIdx.x;
  const int w = tid >> 6, l = tid & 63;
  const int j0 = blockIdx.x * CPB;
  const int rbase = (w << 9) + (l << 3);
  const float dt = tptr[0] * (1.0f / STEPS);
  const float csv0 = 0.f, csv1 = 0.5f, csv2 = 0.5f, csv3 = 1.f;

  // prefetch phase 0 weights (W1): one 16B DMA per column per lane-slice
#pragma unroll
  for (int c = 0; c < CPB; ++c)
    load16(Wt1 + ((size_t)(j0 + c) << 12) + rbase, &wlds[c][w << 9]);

  for (int ph = 0; ph < 64; ++ph) {
    const int mode = ph & 3;
    const int ev = ph >> 2;
    const int s = ev & 3;
    const float* __restrict__ xin  = (ph & 1) ? xB : xA;
    float* __restrict__ xout = (ph & 1) ? xA : xB;

    if (ph) {   // ---- global barrier #ph (weights DMA stays in flight) ----
      asm volatile("s_barrier" ::: "memory");
      if (tid == 0) {
        const unsigned want = (unsigned)ph;
        const unsigned prev = __hip_atomic_fetch_add(
            &bar[0], 1u, __ATOMIC_ACQ_REL, __HIP_MEMORY_SCOPE_AGENT);
        if (prev == want * NBLK - 1) {
          __hip_atomic_store(&bar[1], want, __ATOMIC_RELEASE,
                             __HIP_MEMORY_SCOPE_AGENT);
        } else {
          unsigned long long guard = 0;
          while (__hip_atomic_load(&bar[1], __ATOMIC_ACQUIRE,
                                   __HIP_MEMORY_SCOPE_AGENT) < want) {
            __builtin_amdgcn_s_sleep(2);
            if (++guard > (1ull << 20)) break;   // anti-hang bailout
          }
        }
      }
      asm volatile("s_barrier" ::: "memory");
    }

    // x slice: agent-scope loads (LLC is the coherence point; no fences)
    float xa[8];
#pragma unroll
    for (int e = 0; e < 8; ++e) xa[e] = aload(xin + rbase + e);

    asm volatile("s_waitcnt vmcnt(0)" ::: "memory");  // own weight DMA landed

    float acc[CPB];
#pragma unroll
    for (int c = 0; c < CPB; ++c) {
      const us8 wv = *reinterpret_cast<const us8*>(&wlds[c][rbase]);
      float a = 0.f;
#pragma unroll
      for (int e = 0; e < 8; ++e) a = fmaf(bf2f(wv[e]), xa[e], a);
      acc[c] = a;
    }
    __syncthreads();   // all waves' weight ds_reads done -> red may alias
#pragma unroll
    for (int c = 0; c < CPB; ++c) {
#pragma unroll
      for (int o = 32; o >= 1; o >>= 1) acc[c] += __shfl_down(acc[c], o);
    }
    if (l == 0) {
#pragma unroll
      for (int c = 0; c < CPB; ++c) red[(w << 3) + c] = acc[c];
    }
    __syncthreads();

    if (tid < CPB) {   // ---- epilogue: 8 lanes, one output column each ----
      const int j = j0 + tid;
      float dot = 0.f;
#pragma unroll
      for (int g2 = 0; g2 < 8; ++g2) dot += red[(g2 << 3) + tid];
      const float csv_cur = (s == 0) ? csv0 : (s == 1 ? csv1 : (s == 2 ? csv2 : csv3));
      const float tsv = (float)(ev >> 2) + csv_cur;
      const float tcoef = (mode <= 1) ? tsv * dt : 1.0f;
      const float a = fmaf(tcoef, (ph & 1) ? T2v[j] : T1v[j], dot);
      float xnew;
      if (mode == 0) {                       // P1: u1; x2 = sig(u1)
        xnew = sigf(a + cp1[j]);
      } else if (mode == 1) {                // P2: f; v1 = s0'(ys)*f
        const float fv = a + cp2[j];
        fbuf[j] = fv;
        const float s0 = aload(xout + j);    // = sig(ystage), P1's input
        xnew = s0 * (1.f - s0) * fv;
      } else if (mode == 2) {                // P3: du1; v2 = s1'(u1)*du1
        const float s1 = aload(xout + j);    // = sig(u1), P2's input
        xnew = s1 * (1.f - s1) * a;
      } else {                               // P4: df; RK bookkeeping
        red[64 + tid] = a * a;
        const float fc = fbuf[j];
        float y = ycur[j];
        if (s == 0)      ksum[j] = fc;
        else if (s < 3)  ksum[j] = fmaf(2.f, fc, ksum[j]);
        else { y = fmaf(dt * (1.f / 6.f), ksum[j] + fc, y); ycur[j] = y; }
        const float csvn = (s == 0) ? csv1 : (s == 1 ? csv2 : (s == 2 ? csv3 : csv0));
        xnew = sigf(fmaf(csvn * dt, fc, y)); // next stage's x1
        if (ph == 63) out[j] = y;            // final state -> output
      }
      astore(xout + j, xnew);
    }
    __syncthreads();
    if (mode == 3 && tid == 0) {
      float v = 0.f;
#pragma unroll
      for (int q = 0; q < CPB; ++q) v += red[64 + q];
      atomicAdd(&rk[ev], v);
    }
    __syncthreads();   // rk/red reads done before DMA reuses wave-0 slice

    if (ph < 63) {     // prefetch next phase's weights (overlaps the barrier)
      const unsigned short* __restrict__ Wn = ((ph + 1) & 1) ? Wt2 : Wt1;
#pragma unroll
      for (int c = 0; c < CPB; ++c)
        load16(Wn + ((size_t)(j0 + c) << 12) + rbase, &wlds[c][w << 9]);
    }
  }
}

// ---------------------------------------------------------------------------
// out[N] = RK4-weighted integral of mean(df^2).
// ---------------------------------------------------------------------------
__global__ void k_out(const float* __restrict__ rk, const float* __restrict__ tptr,
                      float* __restrict__ out) {
  if (threadIdx.x == 0) {
    const float dt = tptr[0] * (1.0f / STEPS);
    float r = 0.f;
    for (int st = 0; st < STEPS; ++st)
      r += rk[4 * st] + 2.f * rk[4 * st + 1] + 2.f * rk[4 * st + 2] + rk[4 * st + 3];
    out[N] = r * (dt / 6.f) * (1.0f / N);
  }
}

// ---------------------------------------------------------------------------
extern "C" void kernel_launch(void* const* d_in, const int* in_sizes, int n_in,
                              void* d_out, int out_size, void* d_ws, size_t ws_size,
                              hipStream_t stream) {
  const float* h  = (const float*)d_in[0];
  const float* t  = (const float*)d_in[1];
  const float* c  = (const float*)d_in[2];
  const float* W1 = (const float*)d_in[3];
  const float* b1 = (const float*)d_in[4];
  const float* W2 = (const float*)d_in[5];
  const float* b2 = (const float*)d_in[6];
  float* out = (float*)d_out;

  // ws: Wt1 | Wt2 (bf16 col-major, 33.55 MB each) | fp32 vectors (~300 KB).
  char* ws = (char*)d_ws;
  const size_t wb = (size_t)N * N * sizeof(unsigned short);
  unsigned short* Wt1 = (unsigned short*)ws;
  unsigned short* Wt2 = (unsigned short*)(ws + wb);
  float* fp = (float*)(ws + 2 * wb);
  float* xA   = fp;
  float* xB   = xA + N;
  float* cp1  = xB + N;
  float* cp2  = cp1 + N;
  float* fbuf = cp2 + N;
  float* ycur = fbuf + N;
  float* ksum = ycur + N;
  float* T1   = ksum + N;
  float* T2   = T1 + N;
  float* rk   = T2 + N;                     // 16 floats
  unsigned int* bar = (unsigned int*)(rk + 16);  // {cnt, flag}

  k_init<<<16, 256, 0, stream>>>(h, W1, W2, b1, b2, ycur, cp1, cp2, xA, T1, T2,
                                 rk, bar);
  k_conv<<<dim3(64, 64, 2), 256, 0, stream>>>(W1, W2, Wt1, Wt2);
  k_cpart<<<dim3(16, 8, 2), 256, 0, stream>>>(W1, W2, c, cp1, cp2);

  k_ode<<<NBLK, TPB, 0, stream>>>(Wt1, Wt2, T1, T2, cp1, cp2, xA, xB, fbuf,
                                  ycur, ksum, rk, t, bar, out);
  k_out<<<1, 64, 0, stream>>>(rk, t, out);
}